// Round 1
// baseline (225.396 us; speedup 1.0000x reference)
//
#include <hip/hip_runtime.h>

// N-gram embedding mean on gfx950. One wave per word.
// R(polish): dwordx4 gather (2 rows / load instr) + 2-deep group pipeline.
// - word id, all 24 ngram ids, and cnt pinned scalar via readfirstlane.
// - lanes 0-31 handle even slots, lanes 32-63 odd slots; each lane loads a
//   float4 (16B) => one load instruction fetches 2 full 512B rows.
// - 3 groups of 8 rows (4 pair-loads each) pipelined 2-deep:
//   issue G0, issue G1, consume G0, issue G2, consume G1, consume G2.
//   Up to 8KB in flight per wave, no vmcnt(0) drains between groups.
// - buffer = 2 groups (32 VGPR) so total stays <=64 VGPR -> 32 waves/CU
//   (pinned by __launch_bounds__(256, 8)).
// - padding slots point at row 0: loaded (L1-hot) but masked via fma.
// - cross-half combine with __shfl_xor(.,32); half-wave dwordx4 nontemporal
//   store (write-once output; avoid evicting table lines from L3).
#define NUM_WORDS 32768   // B*S = 16*2048
#define KMAX 24

typedef float f4 __attribute__((ext_vector_type(4)));

__global__ __launch_bounds__(256, 8) void ngram_emb_kernel(
    const int* __restrict__ word_idx,      // [B*S]
    const int* __restrict__ ngram_ids,     // [V, K]
    const int* __restrict__ ngram_counts,  // [V]
    const float* __restrict__ emb_table,   // [NG, E]
    float* __restrict__ out)               // [B*S, E]
{
    const int gtid = blockIdx.x * blockDim.x + threadIdx.x;
    const int word = gtid >> 6;            // one wave per word
    const int lane = threadIdx.x & 63;
    const int half = lane >> 5;            // 0: even slot of pair, 1: odd slot
    const int col  = lane & 31;            // float4 chunk within the 512B row

    // wave-uniform scalars (full wave active here — readfirstlane is safe)
    const int w   = __builtin_amdgcn_readfirstlane(word_idx[word]);
    const int cnt = __builtin_amdgcn_readfirstlane(ngram_counts[w]);
    const int* ids = ngram_ids + w * KMAX;

    int rr[KMAX];
#pragma unroll
    for (int k = 0; k < KMAX; ++k)
        rr[k] = __builtin_amdgcn_readfirstlane(ids[k]);

    const f4* tbl = (const f4*)emb_table;  // row stride = 32 float4

    f4    v[8];                            // 2 groups of 4 pair-loads in flight
    float m[8];
    f4    acc = (f4){0.f, 0.f, 0.f, 0.f};

    // Issue 4 pair-loads of group G into buffer slots BUF..BUF+3.
    // Pair j covers rows rr[G*8+2j] (lanes 0-31) and rr[G*8+2j+1] (lanes 32-63).
#define ISSUE(G, BUF)                                               \
    _Pragma("unroll")                                               \
    for (int j = 0; j < 4; ++j) {                                   \
        const int re = rr[(G)*8 + 2*j];                             \
        const int ro = rr[(G)*8 + 2*j + 1];                         \
        const int r  = half ? ro : re;     /* v_cndmask of sgprs */ \
        m[(BUF) + j] = (r != 0) ? 1.f : 0.f;                        \
        v[(BUF) + j] = tbl[(long)r * 32 + col];                     \
    }

#define CONSUME(BUF)                                                \
    _Pragma("unroll")                                               \
    for (int j = 0; j < 4; ++j)                                     \
        acc += m[(BUF) + j] * v[(BUF) + j];   /* contracts to fma */

    ISSUE(0, 0);                            // rows 0-7, always
    if (cnt > 8)  { ISSUE(1, 4); }          // rows 8-15 in flight behind G0
    CONSUME(0);
    if (cnt > 16) { ISSUE(2, 0); }          // rows 16-23, reuse G0 buffers
    if (cnt > 8)  { CONSUME(4); }
    if (cnt > 16) { CONSUME(0); }

    // lanes l and l^32 hold the same 4 columns (even vs odd rows) — combine
    acc.x += __shfl_xor(acc.x, 32);
    acc.y += __shfl_xor(acc.y, 32);
    acc.z += __shfl_xor(acc.z, 32);
    acc.w += __shfl_xor(acc.w, 32);

    if (half == 0) {                        // 32 lanes x 16B = 512B row
        const float inv = 1.0f / (float)cnt;
        f4 o = acc * inv;
        __builtin_nontemporal_store(o, (f4*)out + (long)word * 32 + col);
    }
}

extern "C" void kernel_launch(void* const* d_in, const int* in_sizes, int n_in,
                              void* d_out, int out_size, void* d_ws, size_t ws_size,
                              hipStream_t stream) {
    const int*   word_idx     = (const int*)d_in[0];
    const int*   ngram_ids    = (const int*)d_in[1];
    const int*   ngram_counts = (const int*)d_in[2];
    const float* emb_table    = (const float*)d_in[3];
    float*       out          = (float*)d_out;

    const int threads = 256;
    const int blocks  = (NUM_WORDS * 64) / threads;  // 8192
    ngram_emb_kernel<<<blocks, threads, 0, stream>>>(
        word_idx, ngram_ids, ngram_counts, emb_table, out);
}

// Round 2
// 169.026 us; speedup vs baseline: 1.3335x; 1.3335x over previous
//
#include <hip/hip_runtime.h>

// N-gram embedding mean on gfx950. One wave per word.
// R2(polish): round-0 structure (proven 44us dispatch) + 16-row rolling
// in-flight buffer. Round-1 post-mortem: __launch_bounds__(256,8) forced a
// 32-VGPR cap -> the f4 pipeline buffer spilled to scratch (WRITE_SIZE
// 240MB vs 17MB of real output) -> 2.4x regression. This version keeps
// VGPR pressure ~48 (<=64 -> full 32 waves/CU naturally, no min-wave bound).
// - word id & all 24 ngram ids pinned scalar via readfirstlane -> every
//   gather is global_load_dwordx2 with SGPR base + lane offset (no per-lane
//   64-bit address math, no divergence).
// - rows processed in 3 groups of 8, pipelined 2-deep with a rolling
//   16-slot buffer: issue G0, issue G1, consume G0, issue G2 (reuse G0
//   slots), consume G1, consume G2. Up to 16 rows (8KB) in flight per
//   wave; no vmcnt(0) drain between groups (compiler emits vmcnt(8)).
// - uniform cnt branches skip whole groups (cnt is wave-uniform).
// - padding slots point at row 0: loaded (L1-hot) but masked via fmaf.
#define NUM_WORDS 32768   // B*S = 16*2048
#define KMAX 24
#define GROUP 8

__global__ __launch_bounds__(256) void ngram_emb_kernel(
    const int* __restrict__ word_idx,      // [B*S]
    const int* __restrict__ ngram_ids,     // [V, K]
    const int* __restrict__ ngram_counts,  // [V]
    const float* __restrict__ emb_table,   // [NG, E]
    float* __restrict__ out)               // [B*S, E]
{
    const int gtid = blockIdx.x * blockDim.x + threadIdx.x;
    const int word = gtid >> 6;            // one wave per word
    const int lane = threadIdx.x & 63;     // float2 chunk within the 512B row

    // wave-uniform scalars (full wave active here — readfirstlane is safe)
    const int w   = __builtin_amdgcn_readfirstlane(word_idx[word]);
    const int cnt = ngram_counts[w];       // uniform (scalar base)
    const int* ids = ngram_ids + w * KMAX;

    int rr[KMAX];
#pragma unroll
    for (int k = 0; k < KMAX; ++k)
        rr[k] = __builtin_amdgcn_readfirstlane(ids[k]);

    const float2* tbl = (const float2*)emb_table;   // row stride = 64 float2

    float2 v[2 * GROUP];                   // rolling 16-row in-flight buffer
    float  m[2 * GROUP];
    float ax = 0.f, ay = 0.f;

    // Issue 8 row loads of group G into buffer slots BUF..BUF+7.
    // r is scalar -> address is SGPR base + lane*8 (efficient form).
#define ISSUE(G, BUF)                                               \
    _Pragma("unroll")                                               \
    for (int j = 0; j < GROUP; ++j) {                               \
        const int r = rr[(G)*GROUP + j];   /* scalar row id (0 = pad) */ \
        m[(BUF) + j] = r ? 1.f : 0.f;                               \
        v[(BUF) + j] = tbl[(long)r * 64 + lane];                    \
    }

#define CONSUME(BUF)                                                \
    _Pragma("unroll")                                               \
    for (int j = 0; j < GROUP; ++j) {                               \
        ax = fmaf(m[(BUF) + j], v[(BUF) + j].x, ax);                \
        ay = fmaf(m[(BUF) + j], v[(BUF) + j].y, ay);                \
    }

    ISSUE(0, 0);                           // rows 0-7: always present (cnt>=1)
    if (cnt > 8) ISSUE(1, 8);              // rows 8-15 in flight behind G0
    CONSUME(0);                            // waits ~vmcnt(8): G1 stays in flight
    if (cnt > 16) {
        ISSUE(2, 0);                       // rows 16-23, reuse G0 slots
        CONSUME(8);                        // G2 stays in flight
        CONSUME(0);
    } else if (cnt > 8) {
        CONSUME(8);
    }

    const float inv = 1.0f / (float)cnt;
    float2 o; o.x = ax * inv; o.y = ay * inv;
    ((float2*)out)[(long)word * 64 + lane] = o;    // 64 lanes x 8B = 512B row
}

extern "C" void kernel_launch(void* const* d_in, const int* in_sizes, int n_in,
                              void* d_out, int out_size, void* d_ws, size_t ws_size,
                              hipStream_t stream) {
    const int*   word_idx     = (const int*)d_in[0];
    const int*   ngram_ids    = (const int*)d_in[1];
    const int*   ngram_counts = (const int*)d_in[2];
    const float* emb_table    = (const float*)d_in[3];
    float*       out          = (float*)d_out;

    const int threads = 256;
    const int blocks  = (NUM_WORDS * 64) / threads;  // 8192
    ngram_emb_kernel<<<blocks, threads, 0, stream>>>(
        word_idx, ngram_ids, ngram_counts, emb_table, out);
}